// Round 7
// baseline (624.546 us; speedup 1.0000x reference)
//
#include <hip/hip_runtime.h>
#include <hip/hip_bf16.h>
#include <cstdint>

#define OUT_LD 3584
#define NBLK 512
#define MAGIC 0x13572468u

typedef __bf16 bf16x8 __attribute__((ext_vector_type(8)));
typedef float  f32x4  __attribute__((ext_vector_type(4)));

__device__ __forceinline__ short f2bf(float v) {
  __hip_bfloat16 h = __float2bfloat16(v);
  return *reinterpret_cast<short*>(&h);
}

__device__ __forceinline__ void async16(const short* g, short* l) {
  __builtin_amdgcn_global_load_lds(
      (const __attribute__((address_space(1))) unsigned int*)g,
      (__attribute__((address_space(3))) unsigned int*)l, 16, 0, 0);
}

struct __align__(16) SBuf {
  short sA[3][64 * 64];
  short sB[3][64 * 64];
};

union __align__(16) LdsPool {
  SBuf g;               // 48 KB gemm staging
  short tr[32][33];     // prep transpose tile
};

// device-scope grid barrier. sync[0..3] = phase counters, sync[4] = ready flag.
// Block 0 zeroes counters then releases MAGIC; ws is re-poisoned 0xAA per call
// so this re-initializes every launch. threadfence on both sides gives
// cross-XCD release/acquire for the data written before the barrier.
__device__ __forceinline__ void gsync(unsigned int* s, int ph) {
  __threadfence();
  __syncthreads();
  if (threadIdx.x == 0) {
    if (ph == 0) {
      while (__hip_atomic_load(&s[4], __ATOMIC_ACQUIRE, __HIP_MEMORY_SCOPE_AGENT) != MAGIC)
        __builtin_amdgcn_s_sleep(2);
    }
    __hip_atomic_fetch_add(&s[ph], 1u, __ATOMIC_ACQ_REL, __HIP_MEMORY_SCOPE_AGENT);
    while (__hip_atomic_load(&s[ph], __ATOMIC_ACQUIRE, __HIP_MEMORY_SCOPE_AGENT) < NBLK)
      __builtin_amdgcn_s_sleep(2);
  }
  __syncthreads();
  __threadfence();
}

// ---------------------------------------------------------------------------
// 64x64-tile, 256-thr (4 waves 2x2) GEMM, 3-buffer pipeline with COUNTED
// vmcnt (T3+T4). LDS XOR-swizzled both-sides (T2, rule 21). Identical to the
// round-6 body (proven correct, absmax 0.03125).
// ---------------------------------------------------------------------------
template<bool RELU>
__device__ __forceinline__ void gemm64(
    SBuf& s, const short* __restrict__ A, const short* __restrict__ B, int K,
    int bm, int bn, const float* __restrict__ bias, int outoff,
    float* __restrict__ fout, short* __restrict__ cbf)
{
  const int tid  = threadIdx.x;
  const int lane = tid & 63;
  const int wid  = tid >> 6;
  const int wr   = (wid >> 1) * 32;
  const int wc   = (wid & 1) * 32;
  const int fr   = lane & 15;
  const int fkg  = lane >> 4;

  const int srow = tid >> 3;
  const int sg   = (tid & 7) ^ (srow & 7);
  const short* ga0 = A + (size_t)(bm + srow) * K + sg * 8;
  const short* gb0 = B + (size_t)(bn + srow) * K + sg * 8;

  f32x4 acc[2][2] = {};
  const int nk = K >> 6;

  auto stage = [&](int buf, int kt) {
    const int koff = kt * 64;
    async16(ga0 + koff,                  &s.sA[buf][tid * 8]);
    async16(ga0 + 32 * (size_t)K + koff, &s.sA[buf][2048 + tid * 8]);
    async16(gb0 + koff,                  &s.sB[buf][tid * 8]);
    async16(gb0 + 32 * (size_t)K + koff, &s.sB[buf][2048 + tid * 8]);
  };

  stage(0, 0);
  stage(1, 1);
  for (int kt = 0; kt < nk; ++kt) {
    const int cur = kt % 3;
    if (kt < nk - 1) asm volatile("s_waitcnt vmcnt(4)" ::: "memory");
    else             asm volatile("s_waitcnt vmcnt(0)" ::: "memory");
    __builtin_amdgcn_s_barrier();
    __builtin_amdgcn_s_setprio(1);
    #pragma unroll
    for (int kk = 0; kk < 2; ++kk) {
      bf16x8 a[2], b[2];
      #pragma unroll
      for (int i = 0; i < 2; ++i) {
        const int row = wr + i * 16 + fr;
        a[i] = *(const bf16x8*)((const char*)&s.sA[cur][0] +
                 row * 128 + (((kk * 4 + fkg) ^ (row & 7)) * 16));
      }
      #pragma unroll
      for (int j = 0; j < 2; ++j) {
        const int row = wc + j * 16 + fr;
        b[j] = *(const bf16x8*)((const char*)&s.sB[cur][0] +
                 row * 128 + (((kk * 4 + fkg) ^ (row & 7)) * 16));
      }
      #pragma unroll
      for (int i = 0; i < 2; ++i)
        #pragma unroll
        for (int j = 0; j < 2; ++j)
          acc[i][j] = __builtin_amdgcn_mfma_f32_16x16x32_bf16(a[i], b[j], acc[i][j], 0, 0, 0);
    }
    __builtin_amdgcn_s_setprio(0);
    if (kt + 2 < nk) {
      __builtin_amdgcn_s_barrier();
      stage((kt + 2) % 3, kt + 2);
    }
  }

  const int q0 = (lane >> 4) * 4;
  #pragma unroll
  for (int i = 0; i < 2; ++i) {
    #pragma unroll
    for (int j = 0; j < 2; ++j) {
      const int col = bn + wc + j * 16 + fr;
      #pragma unroll
      for (int q = 0; q < 4; ++q) {
        const int row = bm + wr + i * 16 + q0 + q;
        float v = acc[i][j][q];
        if (RELU) {
          float rv = v > 0.f ? v : 0.f;
          fout[(size_t)row * OUT_LD + col] = rv;
          cbf[(size_t)row * 512 + col] = f2bf(rv);
        } else {
          fout[(size_t)row * OUT_LD + outoff + col] = v + bias[col];
        }
      }
    }
  }
  __syncthreads();   // LDS safe for next tile's staging
}

// ---------------------------------------------------------------------------
// THE kernel: phase0 prep -> sync -> c1 -> sync -> {c2, eta1} -> sync ->
// {c3, eta2} -> sync -> eta3. 512 blocks x 256 thr, 48 KB LDS (3/CU capacity
// guarantees co-residency of 2/CU-needed grid).
// ---------------------------------------------------------------------------
__global__ __launch_bounds__(256, 2)
void mega(const float* __restrict__ Y, const float* __restrict__ W1,
          const float* __restrict__ W2, const float* __restrict__ W3,
          const float* __restrict__ b1, const float* __restrict__ b2,
          const float* __restrict__ b3, float* __restrict__ out,
          short* Ybf, short* c1bf, short* c2bf, short* c3bf,
          short* W1b, short* W2b, short* W3b,
          short* W1T, short* W2T, short* W3T,
          unsigned int* sync)
{
  __shared__ LdsPool u;
  const int b   = blockIdx.x;
  const int tid = threadIdx.x;

  if (b == 0 && tid == 0) {
    for (int i = 0; i < 4; ++i)
      __hip_atomic_store(&sync[i], 0u, __ATOMIC_RELAXED, __HIP_MEMORY_SCOPE_AGENT);
    __hip_atomic_store(&sync[4], MAGIC, __ATOMIC_RELEASE, __HIP_MEMORY_SCOPE_AGENT);
  }

  // ---- phase 0: prep (cvt + transposes) ----
  {
    const int gtid = b * 256 + tid;          // [0, 131072)
    #pragma unroll
    for (int q = 0; q < 10; ++q) {           // 1310720 float4 jobs
      const int i = q * 131072 + gtid;
      const float* src; short* dst; int off;
      if (i < 1048576)      { src = Y;  dst = Ybf; off = i; }
      else if (i < 1179648) { src = W1; dst = W1b; off = i - 1048576; }
      else if (i < 1245184) { src = W2; dst = W2b; off = i - 1179648; }
      else                  { src = W3; dst = W3b; off = i - 1245184; }
      const float4 v = reinterpret_cast<const float4*>(src)[off];
      short4 o;
      o.x = f2bf(v.x); o.y = f2bf(v.y); o.z = f2bf(v.z); o.w = f2bf(v.w);
      reinterpret_cast<short4*>(dst)[off] = o;
    }
    // 1024 transpose tiles, 2 per block
    for (int t = 2 * b; t < 2 * b + 2; ++t) {
      const float* in; short* outp; int R, C, ti, tj;
      if (t < 512)      { in = W1; outp = W1T; R = 512; C = 1024; ti = t >> 5; tj = t & 31; }
      else if (t < 768) { int l = t - 512; in = W2; outp = W2T; R = 512; C = 512; ti = l >> 4; tj = l & 15; }
      else              { int l = t - 768; in = W3; outp = W3T; R = 512; C = 512; ti = l >> 4; tj = l & 15; }
      const int r0 = ti * 32, c0 = tj * 32;
      const int tx = tid & 31, ty = tid >> 5;
      __syncthreads();
      #pragma unroll
      for (int q = 0; q < 4; ++q)
        u.tr[ty + q * 8][tx] = f2bf(in[(size_t)(r0 + ty + q * 8) * C + c0 + tx]);
      __syncthreads();
      #pragma unroll
      for (int q = 0; q < 4; ++q)
        outp[(size_t)(c0 + ty + q * 8) * R + r0 + tx] = u.tr[tx][ty + q * 8];
    }
  }
  gsync(sync, 0);

  // ---- phase 1: c1 = relu(Y @ W1^T), 512 tiles, K=1024 ----
  {
    const int swz = (b & 7) * 64 + (b >> 3);
    gemm64<true>(u.g, Ybf, W1b, 1024, (swz >> 3) * 64, (swz & 7) * 64,
                 nullptr, 0, out + 2048, c1bf);
  }
  gsync(sync, 1);

  // ---- phase 2: c2 (512) + eta1 (1024), 3 tiles/block ----
  #pragma unroll 1
  for (int t = 0; t < 3; ++t) {
    const int id  = b + t * 512;
    const int swz = (id & 7) * 192 + (id >> 3);
    if (swz < 512) {
      gemm64<true>(u.g, c1bf, W2b, 512, (swz >> 3) * 64, (swz & 7) * 64,
                   nullptr, 0, out + 2560, c2bf);
    } else {
      const int tt = swz - 512;
      gemm64<false>(u.g, c1bf, W1T, 512, (tt >> 4) * 64, (tt & 15) * 64,
                    b1, 0, out, nullptr);
    }
  }
  gsync(sync, 2);

  // ---- phase 3: c3 (512) + eta2 (512), 2 tiles/block ----
  #pragma unroll 1
  for (int t = 0; t < 2; ++t) {
    const int id  = b + t * 512;
    const int swz = (id & 7) * 128 + (id >> 3);
    if (swz < 512) {
      gemm64<true>(u.g, c2bf, W3b, 512, (swz >> 3) * 64, (swz & 7) * 64,
                   nullptr, 0, out + 3072, c3bf);
    } else {
      const int tt = swz - 512;
      gemm64<false>(u.g, c2bf, W2T, 512, (tt >> 3) * 64, (tt & 7) * 64,
                    b2, 1024, out, nullptr);
    }
  }
  gsync(sync, 3);

  // ---- phase 4: eta3 (512) ----
  {
    const int swz = (b & 7) * 64 + (b >> 3);
    gemm64<false>(u.g, c3bf, W3T, 512, (swz >> 3) * 64, (swz & 7) * 64,
                  b3, 1536, out, nullptr);
  }
}

extern "C" void kernel_launch(void* const* d_in, const int* in_sizes, int n_in,
                              void* d_out, int out_size, void* d_ws, size_t ws_size,
                              hipStream_t stream) {
  const float* Y  = (const float*)d_in[0];
  const float* W1 = (const float*)d_in[1];
  const float* W2 = (const float*)d_in[2];
  const float* W3 = (const float*)d_in[3];
  const float* b1 = (const float*)d_in[4];
  const float* b2 = (const float*)d_in[5];
  const float* b3 = (const float*)d_in[6];
  float* out = (float*)d_out;

  if (ws_size < 25165952) return;  // 24 MB scratch + sync words

  char* ws = (char*)d_ws;
  short* Ybf  = (short*)(ws);                  // [4096][1024]
  short* c1bf = (short*)(ws + 8388608);        // [4096][512]
  short* c2bf = (short*)(ws + 12582912);       // [4096][512]
  short* c3bf = (short*)(ws + 16777216);       // [4096][512]
  short* W1b  = (short*)(ws + 20971520);       // [512][1024]
  short* W2b  = (short*)(ws + 22020096);       // [512][512]
  short* W3b  = (short*)(ws + 22544384);       // [512][512]
  short* W1T  = (short*)(ws + 23068672);       // [1024][512]
  short* W2T  = (short*)(ws + 24117248);       // [512][512]
  short* W3T  = (short*)(ws + 24641536);       // [512][512]
  unsigned int* sync = (unsigned int*)(ws + 25165824);

  mega<<<NBLK, 256, 0, stream>>>(Y, W1, W2, W3, b1, b2, b3, out,
                                 Ybf, c1bf, c2bf, c3bf,
                                 W1b, W2b, W3b, W1T, W2T, W3T, sync);
}